// Round 3
// baseline (819.132 us; speedup 1.0000x reference)
//
#include <hip/hip_runtime.h>
#include <stdint.h>

typedef unsigned short u16;
typedef unsigned int   u32;
typedef unsigned long long u64;

typedef __bf16 v8bf __attribute__((ext_vector_type(8)));
typedef float  v4f  __attribute__((ext_vector_type(4)));

// ---- problem constants ----
#define NBATCH 32
#define NCH    512
#define FH     50
#define FW     37
#define PIX    1850        // 50*37
#define MTOT   59200       // 32*1850
#define KTOT   4608        // 512*9
#define HP     52          // padded H
#define WP     39          // padded W
#define NG     20
#define W3N    (NCH*KTOT)  // 2359296
#define WCBN   (64*512)    // padded head weights (rows 54..63 zero)
#define BORDN  364544      // 32*178*64 border uint4 writes
#define NT     72          // K-tiles of 64 in conv GEMM

#define PROB_N 1065600     // 32*18*1850
#define LC_IDX 3196800
#define LL_IDX 3196801

__device__ __forceinline__ u16 f2bf(float f) {          // round-to-nearest-even
    u32 u = __float_as_uint(f);
    u += 0x7fffu + ((u >> 16) & 1u);
    return (u16)(u >> 16);
}

// async global->LDS, 16B per lane. LDS dst = wave-uniform base + lane*16 (m104).
__device__ __forceinline__ void gl_lds16(const u16* g, u16* l) {
    __builtin_amdgcn_global_load_lds((const __attribute__((address_space(1))) u32*)g,
                                     (__attribute__((address_space(3))) u32*)l,
                                     16, 0, 0);
}

// window/channel offset of K-tile T (elements into fpad row base)
__device__ __forceinline__ int offA_of(int T, int kh) {
    const int dydx = T >> 3;              // 3x3 position (64 | 512)
    const int ci0  = (T & 7) << 6;        // channel base within dydx
    return ((dydx / 3) * WP + (dydx % 3)) * NCH + ci0 + kh * 32;
}

// ---------------------------------------------------------------------------
// feats NCHW fp32 -> zero-padded NHWC bf16  [B][52][39][512] (interior only)
// ---------------------------------------------------------------------------
__global__ __launch_bounds__(256) void pad_kernel(const float* __restrict__ feats,
                                                  u16* __restrict__ fpad) {
    __shared__ float t[64][65];
    const int b  = blockIdx.z;
    const int c0 = blockIdx.y * 64;
    const int p0 = blockIdx.x * 64;
    const int tid = threadIdx.x;
    {
        const int cl = tid >> 2, seg = tid & 3;
        const float* src = feats + ((size_t)b * NCH + c0 + cl) * PIX;
        const int pbase = p0 + seg * 16;
        #pragma unroll
        for (int i = 0; i < 16; i++) {
            int p = pbase + i;
            t[cl][seg * 16 + i] = (p < PIX) ? src[p] : 0.f;
        }
    }
    __syncthreads();
    {
        const int pl = tid >> 2, cs = tid & 3;
        const int p = p0 + pl;
        if (p < PIX) {
            const int h = p / FW, w = p % FW;
            size_t dst = (((size_t)b * HP + h + 1) * WP + (w + 1)) * NCH + c0 + cs * 16;
            u32 pk[8];
            #pragma unroll
            for (int i = 0; i < 8; i++) {
                u32 lo = f2bf(t[cs * 16 + 2 * i][pl]);
                u32 hi = f2bf(t[cs * 16 + 2 * i + 1][pl]);
                pk[i] = lo | (hi << 16);
            }
            *(uint4*)&fpad[dst]     = make_uint4(pk[0], pk[1], pk[2], pk[3]);
            *(uint4*)&fpad[dst + 8] = make_uint4(pk[4], pk[5], pk[6], pk[7]);
        }
    }
}

// ---------------------------------------------------------------------------
// merged prep: W3 repack + head-weight repack (zero-padded to 64 rows) +
// fpad border zeroing + loss-scalar zeroing. One launch, no memsets.
// ---------------------------------------------------------------------------
__global__ void prep_kernel(const float* __restrict__ w3, const float* __restrict__ wcls,
                            const float* __restrict__ wloc,
                            u16* __restrict__ wbt, u16* __restrict__ wcb,
                            u16* __restrict__ fpad, float* __restrict__ out) {
    int t = blockIdx.x * 256 + threadIdx.x;
    if (t < 2) out[LC_IDX + t] = 0.f;
    if (t < W3N) {
        int co = t / KTOT, k = t % KTOT;
        int dydx = k >> 9, ci = k & 511;
        wbt[t] = f2bf(w3[((size_t)co * NCH + ci) * 9 + dydx]);
    } else if (t < W3N + WCBN) {
        int t2 = t - W3N;
        int c = t2 >> 9, ci = t2 & 511;
        float v = (c < 18) ? wcls[c * 512 + ci]
                : (c < 54) ? wloc[(c - 18) * 512 + ci] : 0.f;
        wcb[t2] = f2bf(v);
    } else if (t < W3N + WCBN + BORDN) {
        int t3 = t - (W3N + WCBN);
        int c8 = t3 & 63;
        int pi = (t3 >> 6) % 178;
        int b  = (t3 >> 6) / 178;
        int h, w;
        if (pi < 39)       { h = 0;        w = pi; }
        else if (pi < 78)  { h = 51;       w = pi - 39; }
        else if (pi < 128) { h = pi - 77;  w = 0; }
        else               { h = pi - 127; w = 38; }
        size_t dst = (((size_t)b * HP + h) * WP + w) * NCH + c8 * 8;
        *(uint4*)&fpad[dst] = make_uint4(0, 0, 0, 0);
    }
}

// ---------------------------------------------------------------------------
// conv3x3 + bias + relu as implicit GEMM, bf16 MFMA 16x16x32.
// Round 10: ONE barrier + ONE vmcnt(0) per K-tile (72 total, vs 576 barriers
// in rounds 8/9). All 24 ds_read_b128 + 64 MFMAs of a tile form a single
// straight-line body; the compiler's counted-lgkm scheduling (m97 asm:
// lgkmcnt(4/3/1/0) between ds_read and MFMA) overlaps the LDS-read burst
// with MFMA issue INSIDE the body. Rounds 8/9's phase barriers forced
// CU-wide alternation of LDS-phase and MFMA-phase (they ADD: 2300+2483+sync
// ~= measured 6500 cyc/tile, MfmaUtil pinned ~30% across 3 schedules).
//
// Staging: 8 gl_lds for tile T+1 issued right after the top barrier of body
// T, into the buffer tile T-1 just vacated -> a full body (~2500 cyc) of
// flight time, so the top-of-tile vmcnt(0) is near-free.
// WAR safety: a wave's last MFMA of body T consumes its newest ds_read
// (in-order DS completion => implied lgkmcnt(0) before the barrier), so
// after the top barrier of body T+1 ALL waves' reads of buffer nb are
// complete before any wave's gl_lds overwrites it.
// ---------------------------------------------------------------------------
__global__ __launch_bounds__(512, 2) void conv3x3_mfma(const u16* __restrict__ fpad,
                                                       const u16* __restrict__ wbt,
                                                       const float* __restrict__ b3,
                                                       u16* __restrict__ conv1) {
    __shared__ __align__(16) u16 As[2][2][256][32];   // 64 KB
    __shared__ __align__(16) u16 Bs[2][2][256][32];   // 64 KB

    // 464 blocks, 464 % 8 == 0 -> simple bijective XCD swizzle.
    const int wg     = ((int)blockIdx.x & 7) * 58 + ((int)blockIdx.x >> 3);
    const int n_base = (wg & 1) * 256;
    const int m_base = (wg >> 1) * 256;

    const int tid = threadIdx.x;
    const int w   = tid >> 6;            // wave 0..7
    const int l   = tid & 63;

    // ---- staging addressing: wave w stages rows [w*32, w*32+32), 2 calls ----
    const int sr   = l >> 2;
    const int sseg = (l & 3) ^ ((l >> 3) & 3);
    int rbA[2], rbB[2];
    #pragma unroll
    for (int c = 0; c < 2; c++) {
        const int r  = w * 32 + c * 16 + sr;
        const int m  = m_base + r;
        const int mm = (m < MTOT) ? m : 0;           // junk rows -> pixel 0
        const int b = mm / PIX, p = mm % PIX;
        const int y = p / FW, x = p % FW;
        rbA[c] = ((b * HP + y) * WP + x) * NCH + sseg * 8;
        rbB[c] = (n_base + r) * KTOT + sseg * 8;
    }
    u16* const aBase = &As[0][0][0][0] + w * 1024;   // 32 rows * 32 u16
    u16* const bBase = &Bs[0][0][0][0] + w * 1024;

    // ---- fragment read addressing ----
    const int wm = w >> 2, wn = w & 3;               // 2M x 4N wave grid
    const int lm = l & 15, quad = l >> 4;
    const int psw = (quad ^ ((lm >> 1) & 3)) * 8;    // swizzled phys k-seg
    const u16* const aR = &As[0][0][0][0] + (wm * 128 + lm) * 32 + psw;
    const u16* const bR = &Bs[0][0][0][0] + (wn * 64  + lm) * 32 + psw;

    v4f acc[8][4];
    #pragma unroll
    for (int i = 0; i < 8; i++)
        #pragma unroll
        for (int j = 0; j < 4; j++)
            #pragma unroll
            for (int r = 0; r < 4; r++) acc[i][j][r] = 0.f;

#define STAGE_A(buf, kh, Tp) { \
        const int oA_ = offA_of((Tp), (kh)); \
        u16* const dA_ = aBase + (buf) * 16384 + (kh) * 8192; \
        gl_lds16(fpad + rbA[0] + oA_, dA_); \
        gl_lds16(fpad + rbA[1] + oA_, dA_ + 512); }
#define STAGE_B(buf, kh, Tp) { \
        const int oB_ = (Tp) * 64 + (kh) * 32; \
        u16* const dB_ = bBase + (buf) * 16384 + (kh) * 8192; \
        gl_lds16(wbt + rbB[0] + oB_, dB_); \
        gl_lds16(wbt + rbB[1] + oB_, dB_ + 512); }
#define RD_A(dst, buf, kh, mh) { \
        _Pragma("unroll") \
        for (int i_ = 0; i_ < 4; i_++) \
            dst[i_] = *(const v8bf*)(aR + (buf) * 16384 + (kh) * 8192 + ((mh) * 4 + i_) * 512); }
#define RD_B(dst, buf, kh) { \
        _Pragma("unroll") \
        for (int j_ = 0; j_ < 4; j_++) \
            dst[j_] = *(const v8bf*)(bR + (buf) * 16384 + (kh) * 8192 + j_ * 512); }
#define MM(afv, bfv, mh) { \
        _Pragma("unroll") \
        for (int i_ = 0; i_ < 4; i_++) \
            _Pragma("unroll") \
            for (int j_ = 0; j_ < 4; j_++) \
                acc[(mh) * 4 + i_][j_] = __builtin_amdgcn_mfma_f32_16x16x32_bf16( \
                    afv[i_], bfv[j_], acc[(mh) * 4 + i_][j_], 0, 0, 0); }

    // prologue: stage tile 0 into buffer 0
    STAGE_A(0, 0, 0); STAGE_B(0, 0, 0);
    STAGE_A(0, 1, 0); STAGE_B(0, 1, 0);

    for (int T = 0; T < NT; ++T) {
        const int cb = T & 1;
        const int nb = cb ^ 1;
        asm volatile("s_waitcnt vmcnt(0)" ::: "memory");   // tile T staged (this wave)
        __builtin_amdgcn_s_barrier();                      // ... by all waves
        if (T + 1 < NT) {                                  // stage T+1 into freed buffer
            STAGE_A(nb, 0, T + 1); STAGE_B(nb, 0, T + 1);
            STAGE_A(nb, 1, T + 1); STAGE_B(nb, 1, T + 1);
        }
        v8bf b0[4], b1[4], a00[4], a01[4], a10[4], a11[4];
        RD_B(b0, cb, 0); RD_A(a00, cb, 0, 0); RD_A(a01, cb, 0, 1);
        RD_B(b1, cb, 1); RD_A(a10, cb, 1, 0); RD_A(a11, cb, 1, 1);
        MM(a00, b0, 0);
        MM(a01, b0, 1);
        MM(a10, b1, 0);
        MM(a11, b1, 1);
    }
#undef MM
#undef RD_B
#undef RD_A
#undef STAGE_B
#undef STAGE_A

    // epilogue: bias + relu, store bf16 conv1[m][n]
    #pragma unroll
    for (int nj = 0; nj < 4; nj++) {
        const int n = n_base + wn * 64 + nj * 16 + lm;
        const float bias = b3[n];
        #pragma unroll
        for (int i = 0; i < 8; i++) {
            #pragma unroll
            for (int r = 0; r < 4; r++) {
                const int m = m_base + wm * 128 + i * 16 + quad * 4 + r;
                if (m < MTOT) {
                    float v = acc[i][nj][r] + bias;
                    v = v > 0.f ? v : 0.f;
                    conv1[(size_t)m * NCH + n] = f2bf(v);
                }
            }
        }
    }
}

// ---------------------------------------------------------------------------
// head as MFMA GEMM: M=59200 (128/pixel-block), N=64 (54 used), K=512.
// (unchanged)
// ---------------------------------------------------------------------------
__global__ __launch_bounds__(256) void head_mfma(const u16* __restrict__ conv1,
                                                 const u16* __restrict__ wcb,
                                                 const float* __restrict__ bcls,
                                                 const float* __restrict__ bloc,
                                                 float* __restrict__ out) {
    __shared__ __align__(16) u16 As[128][64];   // 16 KB: A slab (128 m x 64 k)
    __shared__ __align__(16) u16 Bs[64][64];    // 8 KB : B slab (64 n x 64 k)
    __shared__ float ct[128][66];               // 33.8 KB: fp32 C tile

    const int tid = threadIdx.x;
    const int m_base = blockIdx.x * 128;
    const int wave = tid >> 6;
    const int lane = tid & 63;
    const int srow  = tid >> 3;
    const int seg_g = (tid & 7) ^ (srow & 7);

    int rbA[4];
    #pragma unroll
    for (int r = 0; r < 4; r++) {
        int m = m_base + r * 32 + srow;
        int mm = (m < MTOT) ? m : 0;
        rbA[r] = mm * NCH + seg_g * 8;
    }
    int rbB[2];
    #pragma unroll
    for (int r = 0; r < 2; r++)
        rbB[r] = (r * 32 + srow) * NCH + seg_g * 8;

    u16* const asb = &As[0][0] + wave * 512;
    u16* const bsb = &Bs[0][0] + wave * 512;

    const int wn = wave * 16;
    const int lm = lane & 15;
    const int quad = lane >> 4;
    const int x7 = lm & 7;

    v4f acc[8];
    #pragma unroll
    for (int i = 0; i < 8; i++)
        #pragma unroll
        for (int r = 0; r < 4; r++) acc[i][r] = 0.f;

    for (int k0 = 0; k0 < NCH; k0 += 64) {
        #pragma unroll
        for (int r = 0; r < 4; r++)
            gl_lds16(conv1 + rbA[r] + k0, asb + r * 2048);
        #pragma unroll
        for (int r = 0; r < 2; r++)
            gl_lds16(wcb + rbB[r] + k0, bsb + r * 2048);
        __syncthreads();

        #pragma unroll
        for (int kh = 0; kh < 2; kh++) {
            const int ps = (((kh << 2) | quad) ^ x7) * 8;
            v8bf bf = *(const v8bf*)(&Bs[0][0] + (wn + lm) * 64 + ps);
            #pragma unroll
            for (int i = 0; i < 8; i++) {
                v8bf af = *(const v8bf*)(&As[0][0] + (i * 16 + lm) * 64 + ps);
                acc[i] = __builtin_amdgcn_mfma_f32_16x16x32_bf16(af, bf, acc[i], 0, 0, 0);
            }
        }
        __syncthreads();
    }

    // bias + park in fp32 LDS tile
    const int col = wn + lm;
    const float bias = (col < 18) ? bcls[col] : (col < 54) ? bloc[col - 18] : 0.f;
    #pragma unroll
    for (int i = 0; i < 8; i++)
        #pragma unroll
        for (int r = 0; r < 4; r++)
            ct[i * 16 + quad * 4 + r][col] = acc[i][r] + bias;
    __syncthreads();

    // softmax pairs + stores. c = tid>>2 (0..63), 4 pixel-lanes.
    const int c = tid >> 2;
    const int pix4 = tid & 3;
    for (int px = pix4; px < 128; px += 4) {
        const int m = m_base + px;
        if (m >= MTOT) break;
        const int b = m / PIX;
        const int p = m - b * PIX;
        if (c < 9) {
            float s0 = ct[px][c], s1 = ct[px][c + 9];
            float mx = fmaxf(s0, s1);
            float e0 = __expf(s0 - mx), e1 = __expf(s1 - mx);
            float inv = 1.f / (e0 + e1);
            out[((size_t)b * 18 + c) * PIX + p]     = e0 * inv;
            out[((size_t)b * 18 + c + 9) * PIX + p] = e1 * inv;
        } else if (c >= 18 && c < 54) {
            out[(size_t)PROB_N + ((size_t)b * 36 + (c - 18)) * PIX + p] = ct[px][c];
        }
    }
}

// ---------------------------------------------------------------------------
// fused IoU + losses: one block per batch. gt-best keys reduced in LDS.
// (unchanged)
// ---------------------------------------------------------------------------
__global__ __launch_bounds__(256) void iouloss_kernel(const float* __restrict__ anchors,
                                                      const float* __restrict__ gtb,
                                                      const int* __restrict__ idxs,
                                                      int A,
                                                      const float* __restrict__ outr,
                                                      float* __restrict__ out) {
    __shared__ float g[NG * 4];
    __shared__ u64 keys[NG];
    __shared__ int gbest[NG];
    __shared__ float red[8];
    const int b = blockIdx.y;
    const int tid = threadIdx.x;
    if (tid < NG * 4) g[tid] = gtb[b * NG * 4 + tid];
    if (tid < NG) keys[tid] = 0ull;
    __syncthreads();

    // pass 1: per-thread per-GT best key, then block max into LDS
    u64 lk[NG];
    #pragma unroll
    for (int gi = 0; gi < NG; gi++) lk[gi] = 0ull;
    for (int a = tid; a < A; a += 256) {
        const float ax1 = anchors[a * 4 + 0], ay1 = anchors[a * 4 + 1];
        const float ax2 = anchors[a * 4 + 2], ay2 = anchors[a * 4 + 3];
        const float areaA = (ax2 - ax1) * (ay2 - ay1);
        const u64 atag = (u64)(0xFFFFFFFFu - (u32)a);
        #pragma unroll
        for (int gi = 0; gi < NG; gi++) {
            float gx1 = g[gi*4], gy1 = g[gi*4+1], gx2 = g[gi*4+2], gy2 = g[gi*4+3];
            float iw = fmaxf(fminf(ax2, gx2) - fmaxf(ax1, gx1), 0.f);
            float ih = fmaxf(fminf(ay2, gy2) - fmaxf(ay1, gy1), 0.f);
            float inter = iw * ih;
            float areaG = (gx2 - gx1) * (gy2 - gy1);
            float iou = inter / fmaxf(areaA + areaG - inter, 1e-8f);
            u64 key = (((u64)__float_as_uint(iou)) << 32) | atag;
            if (key > lk[gi]) lk[gi] = key;
        }
    }
    #pragma unroll
    for (int gi = 0; gi < NG; gi++) {
        u64 k = lk[gi];
        #pragma unroll
        for (int off = 32; off; off >>= 1) {
            u64 o = __shfl_xor(k, off);
            k = (o > k) ? o : k;
        }
        if ((tid & 63) == 0) atomicMax(&keys[gi], k);
    }
    __syncthreads();
    if (tid < NG) gbest[tid] = (int)(0xFFFFFFFFu - (u32)(keys[tid] & 0xFFFFFFFFull));
    __syncthreads();

    // pass 2: labels + losses
    float lc = 0.f, ll = 0.f;
    for (int a = tid; a < A; a += 256) {
        const float ax1 = anchors[a * 4 + 0], ay1 = anchors[a * 4 + 1];
        const float ax2 = anchors[a * 4 + 2], ay2 = anchors[a * 4 + 3];
        const float areaA = (ax2 - ax1) * (ay2 - ay1);
        float best = -1.f;
        int bg = 0;
        #pragma unroll
        for (int gi = 0; gi < NG; gi++) {
            float gx1 = g[gi*4], gy1 = g[gi*4+1], gx2 = g[gi*4+2], gy2 = g[gi*4+3];
            float iw = fmaxf(fminf(ax2, gx2) - fmaxf(ax1, gx1), 0.f);
            float ih = fmaxf(fminf(ay2, gy2) - fmaxf(ay1, gy1), 0.f);
            float inter = iw * ih;
            float areaG = (gx2 - gx1) * (gy2 - gy1);
            float iou = inter / fmaxf(areaA + areaG - inter, 1e-8f);
            if (iou > best) { best = iou; bg = gi; }
        }
        int lbl = (best > 0.7f) ? 1 : 0;
        if (!lbl) {
            #pragma unroll
            for (int gi = 0; gi < NG; gi++) lbl |= (gbest[gi] == a);
        }
        const int idx = idxs[a];
        const int cpr = idx / PIX;
        const int rem = idx % PIX;
        float p0 = outr[((size_t)b * 18 + cpr) * PIX + rem];
        float p1 = outr[((size_t)b * 18 + cpr + 9) * PIX + rem];
        lc += -logf(lbl ? p1 : p0);
        if (lbl) {
            const int hh = idx / 333;
            const int r2 = idx % 333;
            const int ww = r2 / 9;
            const int c4 = r2 % 9;
            const int pp = hh * FW + ww;
            #pragma unroll
            for (int t = 0; t < 4; t++) {
                float lv = outr[(size_t)PROB_N + ((size_t)b * 36 + c4 * 4 + t) * PIX + pp];
                float d = lv - g[bg * 4 + t];
                float ad = fabsf(d);
                ll += (ad < 1.f) ? 0.5f * d * d : ad - 0.5f;
            }
        }
    }
    #pragma unroll
    for (int off = 32; off; off >>= 1) {
        lc += __shfl_xor(lc, off);
        ll += __shfl_xor(ll, off);
    }
    const int lane = tid & 63, wave = tid >> 6;
    if (lane == 0) { red[wave] = lc; red[4 + wave] = ll; }
    __syncthreads();
    if (tid == 0) {
        float slc = red[0] + red[1] + red[2] + red[3];
        float sll = red[4] + red[5] + red[6] + red[7];
        atomicAdd(&out[LC_IDX], slc * (1.f / (32.f * (float)A)));
        atomicAdd(&out[LL_IDX], sll * (1.f / 256.f));
    }
}

// ---------------------------------------------------------------------------
extern "C" void kernel_launch(void* const* d_in, const int* in_sizes, int n_in,
                              void* d_out, int out_size, void* d_ws, size_t ws_size,
                              hipStream_t stream) {
    const float* feats   = (const float*)d_in[0];
    const float* gtb     = (const float*)d_in[1];
    const float* anchors = (const float*)d_in[2];
    const float* W3      = (const float*)d_in[3];
    const float* b3      = (const float*)d_in[4];
    const float* Wcls    = (const float*)d_in[5];
    const float* bcls    = (const float*)d_in[6];
    const float* Wloc    = (const float*)d_in[7];
    const float* bloc    = (const float*)d_in[8];
    const int*   idxs    = (const int*)d_in[9];
    const int A = in_sizes[9];
    float* out = (float*)d_out;

    char* ws = (char*)d_ws;
    size_t off = 0;
    auto alloc = [&](size_t bytes) -> void* {
        void* p = ws + off;
        off = (off + bytes + 255) & ~(size_t)255;
        return p;
    };
    const size_t fpad_n = (size_t)NBATCH * HP * WP * NCH;     // 33,226,752
    u16* fpad   = (u16*)alloc(fpad_n * 2);
    u16* wbt    = (u16*)alloc((size_t)W3N * 2);
    u16* wcb    = (u16*)alloc((size_t)WCBN * 2);
    u16* conv1  = (u16*)alloc((size_t)MTOT * NCH * 2);

    const int prep_tot = W3N + WCBN + BORDN;
    prep_kernel<<<(prep_tot + 255) / 256, 256, 0, stream>>>(W3, Wcls, Wloc, wbt, wcb, fpad, out);
    pad_kernel<<<dim3(29, 8, NBATCH), 256, 0, stream>>>(feats, fpad);
    conv3x3_mfma<<<464, 512, 0, stream>>>(fpad, wbt, b3, conv1);
    head_mfma<<<463, 256, 0, stream>>>(conv1, wcb, bcls, bloc, out);
    iouloss_kernel<<<dim3(1, NBATCH), 256, 0, stream>>>(anchors, gtb, idxs, A, out, out);
}

// Round 4
// 760.318 us; speedup vs baseline: 1.0774x; 1.0774x over previous
//
#include <hip/hip_runtime.h>
#include <stdint.h>

typedef unsigned short u16;
typedef unsigned int   u32;
typedef unsigned long long u64;

typedef __bf16 v8bf __attribute__((ext_vector_type(8)));
typedef float  v4f  __attribute__((ext_vector_type(4)));

// ---- problem constants ----
#define NBATCH 32
#define NCH    512
#define FH     50
#define FW     37
#define PIX    1850        // 50*37
#define MTOT   59200       // 32*1850
#define KTOT   4608        // 512*9
#define HP     52          // padded H
#define WP     39          // padded W
#define NG     20
#define W3N    (NCH*KTOT)  // 2359296
#define WCBN   (64*512)    // padded head weights (rows 54..63 zero)
#define BORDN  364544      // 32*178*64 border uint4 writes
#define NT     72          // K-tiles of 64 in conv GEMM

#define PROB_N 1065600     // 32*18*1850
#define LC_IDX 3196800
#define LL_IDX 3196801

__device__ __forceinline__ u16 f2bf(float f) {          // round-to-nearest-even
    u32 u = __float_as_uint(f);
    u += 0x7fffu + ((u >> 16) & 1u);
    return (u16)(u >> 16);
}

// async global->LDS, 16B per lane. LDS dst = wave-uniform base + lane*16 (m104).
__device__ __forceinline__ void gl_lds16(const u16* g, u16* l) {
    __builtin_amdgcn_global_load_lds((const __attribute__((address_space(1))) u32*)g,
                                     (__attribute__((address_space(3))) u32*)l,
                                     16, 0, 0);
}

// window/channel offset of K-tile T (full 64-ch row base into fpad)
__device__ __forceinline__ int offA_of(int T) {
    const int dydx = T >> 3;              // 3x3 position
    const int ci0  = (T & 7) << 6;        // channel base within dydx
    return ((dydx / 3) * WP + (dydx % 3)) * NCH + ci0;
}

// 8-slot row swizzle (involution via XOR): permutation of 0..7 over row&7
__device__ __forceinline__ int Srow(int r) {
    return ((r >> 1) & 3) | ((r & 1) << 2);
}

// ---------------------------------------------------------------------------
// feats NCHW fp32 -> zero-padded NHWC bf16  [B][52][39][512] (interior only)
// ---------------------------------------------------------------------------
__global__ __launch_bounds__(256) void pad_kernel(const float* __restrict__ feats,
                                                  u16* __restrict__ fpad) {
    __shared__ float t[64][65];
    const int b  = blockIdx.z;
    const int c0 = blockIdx.y * 64;
    const int p0 = blockIdx.x * 64;
    const int tid = threadIdx.x;
    {
        const int cl = tid >> 2, seg = tid & 3;
        const float* src = feats + ((size_t)b * NCH + c0 + cl) * PIX;
        const int pbase = p0 + seg * 16;
        #pragma unroll
        for (int i = 0; i < 16; i++) {
            int p = pbase + i;
            t[cl][seg * 16 + i] = (p < PIX) ? src[p] : 0.f;
        }
    }
    __syncthreads();
    {
        const int pl = tid >> 2, cs = tid & 3;
        const int p = p0 + pl;
        if (p < PIX) {
            const int h = p / FW, w = p % FW;
            size_t dst = (((size_t)b * HP + h + 1) * WP + (w + 1)) * NCH + c0 + cs * 16;
            u32 pk[8];
            #pragma unroll
            for (int i = 0; i < 8; i++) {
                u32 lo = f2bf(t[cs * 16 + 2 * i][pl]);
                u32 hi = f2bf(t[cs * 16 + 2 * i + 1][pl]);
                pk[i] = lo | (hi << 16);
            }
            *(uint4*)&fpad[dst]     = make_uint4(pk[0], pk[1], pk[2], pk[3]);
            *(uint4*)&fpad[dst + 8] = make_uint4(pk[4], pk[5], pk[6], pk[7]);
        }
    }
}

// ---------------------------------------------------------------------------
// merged prep: W3 repack (k-major: wbt2[T][n][64], T = K-tile of 64) +
// head-weight repack + fpad border zeroing + loss-scalar zeroing.
// ---------------------------------------------------------------------------
__global__ void prep_kernel(const float* __restrict__ w3, const float* __restrict__ wcls,
                            const float* __restrict__ wloc,
                            u16* __restrict__ wbt, u16* __restrict__ wcb,
                            u16* __restrict__ fpad, float* __restrict__ out) {
    int t = blockIdx.x * 256 + threadIdx.x;
    if (t < 2) out[LC_IDX + t] = 0.f;
    if (t < W3N) {
        // wbt2 layout: [T][n][c], k = T*64 + c -> B-tile slabs fully contiguous
        int T = t >> 15;                 // /(512*64)
        int n = (t >> 6) & 511;
        int c = t & 63;
        int k = T * 64 + c;
        int dydx = k >> 9, ci = k & 511;
        wbt[t] = f2bf(w3[((size_t)n * NCH + ci) * 9 + dydx]);
    } else if (t < W3N + WCBN) {
        int t2 = t - W3N;
        int c = t2 >> 9, ci = t2 & 511;
        float v = (c < 18) ? wcls[c * 512 + ci]
                : (c < 54) ? wloc[(c - 18) * 512 + ci] : 0.f;
        wcb[t2] = f2bf(v);
    } else if (t < W3N + WCBN + BORDN) {
        int t3 = t - (W3N + WCBN);
        int c8 = t3 & 63;
        int pi = (t3 >> 6) % 178;
        int b  = (t3 >> 6) / 178;
        int h, w;
        if (pi < 39)       { h = 0;        w = pi; }
        else if (pi < 78)  { h = 51;       w = pi - 39; }
        else if (pi < 128) { h = pi - 77;  w = 0; }
        else               { h = pi - 127; w = 38; }
        size_t dst = (((size_t)b * HP + h) * WP + w) * NCH + c8 * 8;
        *(uint4*)&fpad[dst] = make_uint4(0, 0, 0, 0);
    }
}

// ---------------------------------------------------------------------------
// conv3x3 + bias + relu as implicit GEMM, bf16 MFMA 16x16x32.
// Round 11: STAGING GRANULARITY fix. Rounds 7-10 proved schedule-insensitivity
// (390/392/399/415 us, MfmaUtil 28-31% across 4 structures) -> limiter is
// operand delivery: every stage instr gathered 16 discontiguous 64-B lines
// (A: kh-split pixel rows; B: 9216-B-strided rows) = 1024 x 64-B L2 requests
// per tile per CU ~ 87 req/cyc chip-wide. Fix:
//  - B repacked k-major (wbt2[T][n][64]): B staging = contiguous 1-KB bursts.
//  - A LDS rows widened to 128 B (As[buf][256][64]): each stage instr covers
//    8 pixels x full aligned 128-B chunk.
//  => 512 x 128-B requests per tile (2x fewer, 2x wider).
// 128-B rows wrap the 32 banks exactly, so fragment reads need an 8-slot
// swizzle: S(r) = ((r>>1)&3)|((r&1)<<2) (XOR involution), applied as
// source-pre-swizzle on stage (linear LDS dest, m104) and XOR on reads.
// Read-conflict proof: instr lanes (lm 0..15, quad 0..3), phys slot
// p = (kh*4+quad) ^ S(lm&7): exactly 8 lanes per slot -> conflict-free b128.
// Schedule: round-10 single-barrier body (proven equivalent, simplest).
// ---------------------------------------------------------------------------
__global__ __launch_bounds__(512, 2) void conv3x3_mfma(const u16* __restrict__ fpad,
                                                       const u16* __restrict__ wbt,
                                                       const float* __restrict__ b3,
                                                       u16* __restrict__ conv1) {
    __shared__ __align__(16) u16 As[2][256][64];   // 64 KB
    __shared__ __align__(16) u16 Bs[2][256][64];   // 64 KB

    // 464 blocks, 464 % 8 == 0 -> simple bijective XCD swizzle.
    const int wg     = ((int)blockIdx.x & 7) * 58 + ((int)blockIdx.x >> 3);
    const int n_base = (wg & 1) * 256;
    const int m_base = (wg >> 1) * 256;

    const int tid = threadIdx.x;
    const int w   = tid >> 6;            // wave 0..7
    const int l   = tid & 63;

    // ---- staging addressing: wave w stages rows [w*32, w*32+32) ----
    // per gl_lds instr: 8 rows x 8 phys segs; lane l -> (row=l>>3, ps=l&7);
    // global seg g = ps ^ S(row) so linear LDS write + XOR read agree.
    int rbA[4], rbB[4];
    #pragma unroll
    for (int c = 0; c < 4; c++) {
        const int row = w * 32 + c * 8 + (l >> 3);
        const int g   = (l & 7) ^ Srow(row);
        const int m  = m_base + row;
        const int mm = (m < MTOT) ? m : 0;           // junk rows -> pixel 0
        const int b = mm / PIX, p = mm % PIX;
        const int y = p / FW, x = p % FW;
        rbA[c] = ((b * HP + y) * WP + x) * NCH + g * 8;
        rbB[c] = (n_base + row) * 64 + g * 8;
    }
    u16* const aBase = &As[0][0][0] + w * 2048;   // 32 rows * 64 u16
    u16* const bBase = &Bs[0][0][0] + w * 2048;

    // ---- fragment read addressing ----
    const int wm = w >> 2, wn = w & 3;               // 2M x 4N wave grid
    const int lm = l & 15, quad = l >> 4;
    const int Sl = Srow(lm & 7);
    int ps[2];
    ps[0] = (quad ^ Sl) * 8;                         // kh0 phys seg offset
    ps[1] = ((4 + quad) ^ Sl) * 8;                   // kh1
    const u16* const aR = &As[0][0][0] + (wm * 128 + lm) * 64;
    const u16* const bR = &Bs[0][0][0] + (wn * 64  + lm) * 64;

    v4f acc[8][4];
    #pragma unroll
    for (int i = 0; i < 8; i++)
        #pragma unroll
        for (int j = 0; j < 4; j++)
            #pragma unroll
            for (int r = 0; r < 4; r++) acc[i][j][r] = 0.f;

#define STAGE_A(buf, Tp) { \
        const int oA_ = offA_of(Tp); \
        u16* const dA_ = aBase + (buf) * 16384; \
        gl_lds16(fpad + rbA[0] + oA_, dA_); \
        gl_lds16(fpad + rbA[1] + oA_, dA_ + 512); \
        gl_lds16(fpad + rbA[2] + oA_, dA_ + 1024); \
        gl_lds16(fpad + rbA[3] + oA_, dA_ + 1536); }
#define STAGE_B(buf, Tp) { \
        const u16* const sB_ = wbt + (size_t)(Tp) * 32768; \
        u16* const dB_ = bBase + (buf) * 16384; \
        gl_lds16(sB_ + rbB[0], dB_); \
        gl_lds16(sB_ + rbB[1], dB_ + 512); \
        gl_lds16(sB_ + rbB[2], dB_ + 1024); \
        gl_lds16(sB_ + rbB[3], dB_ + 1536); }
#define RD_A(dst, buf, kh, mh) { \
        _Pragma("unroll") \
        for (int i_ = 0; i_ < 4; i_++) \
            dst[i_] = *(const v8bf*)(aR + (buf) * 16384 + ((mh) * 4 + i_) * 1024 + ps[kh]); }
#define RD_B(dst, buf, kh) { \
        _Pragma("unroll") \
        for (int j_ = 0; j_ < 4; j_++) \
            dst[j_] = *(const v8bf*)(bR + (buf) * 16384 + j_ * 1024 + ps[kh]); }
#define MM(afv, bfv, mh) { \
        _Pragma("unroll") \
        for (int i_ = 0; i_ < 4; i_++) \
            _Pragma("unroll") \
            for (int j_ = 0; j_ < 4; j_++) \
                acc[(mh) * 4 + i_][j_] = __builtin_amdgcn_mfma_f32_16x16x32_bf16( \
                    afv[i_], bfv[j_], acc[(mh) * 4 + i_][j_], 0, 0, 0); }

    // prologue: stage tile 0 into buffer 0
    STAGE_A(0, 0); STAGE_B(0, 0);

    for (int T = 0; T < NT; ++T) {
        const int cb = T & 1;
        const int nb = cb ^ 1;
        asm volatile("s_waitcnt vmcnt(0)" ::: "memory");   // tile T staged (this wave)
        __builtin_amdgcn_s_barrier();                      // ... by all waves
        if (T + 1 < NT) {                                  // stage T+1 into freed buffer
            STAGE_A(nb, T + 1); STAGE_B(nb, T + 1);
        }
        v8bf b0[4], b1[4], a00[4], a01[4], a10[4], a11[4];
        RD_B(b0, cb, 0); RD_A(a00, cb, 0, 0); RD_A(a01, cb, 0, 1);
        RD_B(b1, cb, 1); RD_A(a10, cb, 1, 0); RD_A(a11, cb, 1, 1);
        MM(a00, b0, 0);
        MM(a01, b0, 1);
        MM(a10, b1, 0);
        MM(a11, b1, 1);
    }
#undef MM
#undef RD_B
#undef RD_A
#undef STAGE_B
#undef STAGE_A

    // epilogue: bias + relu, store bf16 conv1[m][n]
    #pragma unroll
    for (int nj = 0; nj < 4; nj++) {
        const int n = n_base + wn * 64 + nj * 16 + lm;
        const float bias = b3[n];
        #pragma unroll
        for (int i = 0; i < 8; i++) {
            #pragma unroll
            for (int r = 0; r < 4; r++) {
                const int m = m_base + wm * 128 + i * 16 + quad * 4 + r;
                if (m < MTOT) {
                    float v = acc[i][nj][r] + bias;
                    v = v > 0.f ? v : 0.f;
                    conv1[(size_t)m * NCH + n] = f2bf(v);
                }
            }
        }
    }
}

// ---------------------------------------------------------------------------
// head as MFMA GEMM: M=59200 (128/pixel-block), N=64 (54 used), K=512.
// (unchanged)
// ---------------------------------------------------------------------------
__global__ __launch_bounds__(256) void head_mfma(const u16* __restrict__ conv1,
                                                 const u16* __restrict__ wcb,
                                                 const float* __restrict__ bcls,
                                                 const float* __restrict__ bloc,
                                                 float* __restrict__ out) {
    __shared__ __align__(16) u16 As[128][64];   // 16 KB: A slab (128 m x 64 k)
    __shared__ __align__(16) u16 Bs[64][64];    // 8 KB : B slab (64 n x 64 k)
    __shared__ float ct[128][66];               // 33.8 KB: fp32 C tile

    const int tid = threadIdx.x;
    const int m_base = blockIdx.x * 128;
    const int wave = tid >> 6;
    const int lane = tid & 63;
    const int srow  = tid >> 3;
    const int seg_g = (tid & 7) ^ (srow & 7);

    int rbA[4];
    #pragma unroll
    for (int r = 0; r < 4; r++) {
        int m = m_base + r * 32 + srow;
        int mm = (m < MTOT) ? m : 0;
        rbA[r] = mm * NCH + seg_g * 8;
    }
    int rbB[2];
    #pragma unroll
    for (int r = 0; r < 2; r++)
        rbB[r] = (r * 32 + srow) * NCH + seg_g * 8;

    u16* const asb = &As[0][0] + wave * 512;
    u16* const bsb = &Bs[0][0] + wave * 512;

    const int wn = wave * 16;
    const int lm = lane & 15;
    const int quad = lane >> 4;
    const int x7 = lm & 7;

    v4f acc[8];
    #pragma unroll
    for (int i = 0; i < 8; i++)
        #pragma unroll
        for (int r = 0; r < 4; r++) acc[i][r] = 0.f;

    for (int k0 = 0; k0 < NCH; k0 += 64) {
        #pragma unroll
        for (int r = 0; r < 4; r++)
            gl_lds16(conv1 + rbA[r] + k0, asb + r * 2048);
        #pragma unroll
        for (int r = 0; r < 2; r++)
            gl_lds16(wcb + rbB[r] + k0, bsb + r * 2048);
        __syncthreads();

        #pragma unroll
        for (int kh = 0; kh < 2; kh++) {
            const int ps = (((kh << 2) | quad) ^ x7) * 8;
            v8bf bf = *(const v8bf*)(&Bs[0][0] + (wn + lm) * 64 + ps);
            #pragma unroll
            for (int i = 0; i < 8; i++) {
                v8bf af = *(const v8bf*)(&As[0][0] + (i * 16 + lm) * 64 + ps);
                acc[i] = __builtin_amdgcn_mfma_f32_16x16x32_bf16(af, bf, acc[i], 0, 0, 0);
            }
        }
        __syncthreads();
    }

    // bias + park in fp32 LDS tile
    const int col = wn + lm;
    const float bias = (col < 18) ? bcls[col] : (col < 54) ? bloc[col - 18] : 0.f;
    #pragma unroll
    for (int i = 0; i < 8; i++)
        #pragma unroll
        for (int r = 0; r < 4; r++)
            ct[i * 16 + quad * 4 + r][col] = acc[i][r] + bias;
    __syncthreads();

    // softmax pairs + stores. c = tid>>2 (0..63), 4 pixel-lanes.
    const int c = tid >> 2;
    const int pix4 = tid & 3;
    for (int px = pix4; px < 128; px += 4) {
        const int m = m_base + px;
        if (m >= MTOT) break;
        const int b = m / PIX;
        const int p = m - b * PIX;
        if (c < 9) {
            float s0 = ct[px][c], s1 = ct[px][c + 9];
            float mx = fmaxf(s0, s1);
            float e0 = __expf(s0 - mx), e1 = __expf(s1 - mx);
            float inv = 1.f / (e0 + e1);
            out[((size_t)b * 18 + c) * PIX + p]     = e0 * inv;
            out[((size_t)b * 18 + c + 9) * PIX + p] = e1 * inv;
        } else if (c >= 18 && c < 54) {
            out[(size_t)PROB_N + ((size_t)b * 36 + (c - 18)) * PIX + p] = ct[px][c];
        }
    }
}

// ---------------------------------------------------------------------------
// fused IoU + losses: one block per batch. gt-best keys reduced in LDS.
// (unchanged)
// ---------------------------------------------------------------------------
__global__ __launch_bounds__(256) void iouloss_kernel(const float* __restrict__ anchors,
                                                      const float* __restrict__ gtb,
                                                      const int* __restrict__ idxs,
                                                      int A,
                                                      const float* __restrict__ outr,
                                                      float* __restrict__ out) {
    __shared__ float g[NG * 4];
    __shared__ u64 keys[NG];
    __shared__ int gbest[NG];
    __shared__ float red[8];
    const int b = blockIdx.y;
    const int tid = threadIdx.x;
    if (tid < NG * 4) g[tid] = gtb[b * NG * 4 + tid];
    if (tid < NG) keys[tid] = 0ull;
    __syncthreads();

    // pass 1: per-thread per-GT best key, then block max into LDS
    u64 lk[NG];
    #pragma unroll
    for (int gi = 0; gi < NG; gi++) lk[gi] = 0ull;
    for (int a = tid; a < A; a += 256) {
        const float ax1 = anchors[a * 4 + 0], ay1 = anchors[a * 4 + 1];
        const float ax2 = anchors[a * 4 + 2], ay2 = anchors[a * 4 + 3];
        const float areaA = (ax2 - ax1) * (ay2 - ay1);
        const u64 atag = (u64)(0xFFFFFFFFu - (u32)a);
        #pragma unroll
        for (int gi = 0; gi < NG; gi++) {
            float gx1 = g[gi*4], gy1 = g[gi*4+1], gx2 = g[gi*4+2], gy2 = g[gi*4+3];
            float iw = fmaxf(fminf(ax2, gx2) - fmaxf(ax1, gx1), 0.f);
            float ih = fmaxf(fminf(ay2, gy2) - fmaxf(ay1, gy1), 0.f);
            float inter = iw * ih;
            float areaG = (gx2 - gx1) * (gy2 - gy1);
            float iou = inter / fmaxf(areaA + areaG - inter, 1e-8f);
            u64 key = (((u64)__float_as_uint(iou)) << 32) | atag;
            if (key > lk[gi]) lk[gi] = key;
        }
    }
    #pragma unroll
    for (int gi = 0; gi < NG; gi++) {
        u64 k = lk[gi];
        #pragma unroll
        for (int off = 32; off; off >>= 1) {
            u64 o = __shfl_xor(k, off);
            k = (o > k) ? o : k;
        }
        if ((tid & 63) == 0) atomicMax(&keys[gi], k);
    }
    __syncthreads();
    if (tid < NG) gbest[tid] = (int)(0xFFFFFFFFu - (u32)(keys[tid] & 0xFFFFFFFFull));
    __syncthreads();

    // pass 2: labels + losses
    float lc = 0.f, ll = 0.f;
    for (int a = tid; a < A; a += 256) {
        const float ax1 = anchors[a * 4 + 0], ay1 = anchors[a * 4 + 1];
        const float ax2 = anchors[a * 4 + 2], ay2 = anchors[a * 4 + 3];
        const float areaA = (ax2 - ax1) * (ay2 - ay1);
        float best = -1.f;
        int bg = 0;
        #pragma unroll
        for (int gi = 0; gi < NG; gi++) {
            float gx1 = g[gi*4], gy1 = g[gi*4+1], gx2 = g[gi*4+2], gy2 = g[gi*4+3];
            float iw = fmaxf(fminf(ax2, gx2) - fmaxf(ax1, gx1), 0.f);
            float ih = fmaxf(fminf(ay2, gy2) - fmaxf(ay1, gy1), 0.f);
            float inter = iw * ih;
            float areaG = (gx2 - gx1) * (gy2 - gy1);
            float iou = inter / fmaxf(areaA + areaG - inter, 1e-8f);
            if (iou > best) { best = iou; bg = gi; }
        }
        int lbl = (best > 0.7f) ? 1 : 0;
        if (!lbl) {
            #pragma unroll
            for (int gi = 0; gi < NG; gi++) lbl |= (gbest[gi] == a);
        }
        const int idx = idxs[a];
        const int cpr = idx / PIX;
        const int rem = idx % PIX;
        float p0 = outr[((size_t)b * 18 + cpr) * PIX + rem];
        float p1 = outr[((size_t)b * 18 + cpr + 9) * PIX + rem];
        lc += -logf(lbl ? p1 : p0);
        if (lbl) {
            const int hh = idx / 333;
            const int r2 = idx % 333;
            const int ww = r2 / 9;
            const int c4 = r2 % 9;
            const int pp = hh * FW + ww;
            #pragma unroll
            for (int t = 0; t < 4; t++) {
                float lv = outr[(size_t)PROB_N + ((size_t)b * 36 + c4 * 4 + t) * PIX + pp];
                float d = lv - g[bg * 4 + t];
                float ad = fabsf(d);
                ll += (ad < 1.f) ? 0.5f * d * d : ad - 0.5f;
            }
        }
    }
    #pragma unroll
    for (int off = 32; off; off >>= 1) {
        lc += __shfl_xor(lc, off);
        ll += __shfl_xor(ll, off);
    }
    const int lane = tid & 63, wave = tid >> 6;
    if (lane == 0) { red[wave] = lc; red[4 + wave] = ll; }
    __syncthreads();
    if (tid == 0) {
        float slc = red[0] + red[1] + red[2] + red[3];
        float sll = red[4] + red[5] + red[6] + red[7];
        atomicAdd(&out[LC_IDX], slc * (1.f / (32.f * (float)A)));
        atomicAdd(&out[LL_IDX], sll * (1.f / 256.f));
    }
}

// ---------------------------------------------------------------------------
extern "C" void kernel_launch(void* const* d_in, const int* in_sizes, int n_in,
                              void* d_out, int out_size, void* d_ws, size_t ws_size,
                              hipStream_t stream) {
    const float* feats   = (const float*)d_in[0];
    const float* gtb     = (const float*)d_in[1];
    const float* anchors = (const float*)d_in[2];
    const float* W3      = (const float*)d_in[3];
    const float* b3      = (const float*)d_in[4];
    const float* Wcls    = (const float*)d_in[5];
    const float* bcls    = (const float*)d_in[6];
    const float* Wloc    = (const float*)d_in[7];
    const float* bloc    = (const float*)d_in[8];
    const int*   idxs    = (const int*)d_in[9];
    const int A = in_sizes[9];
    float* out = (float*)d_out;

    char* ws = (char*)d_ws;
    size_t off = 0;
    auto alloc = [&](size_t bytes) -> void* {
        void* p = ws + off;
        off = (off + bytes + 255) & ~(size_t)255;
        return p;
    };
    const size_t fpad_n = (size_t)NBATCH * HP * WP * NCH;     // 33,226,752
    u16* fpad   = (u16*)alloc(fpad_n * 2);
    u16* wbt    = (u16*)alloc((size_t)W3N * 2);
    u16* wcb    = (u16*)alloc((size_t)WCBN * 2);
    u16* conv1  = (u16*)alloc((size_t)MTOT * NCH * 2);

    const int prep_tot = W3N + WCBN + BORDN;
    prep_kernel<<<(prep_tot + 255) / 256, 256, 0, stream>>>(W3, Wcls, Wloc, wbt, wcb, fpad, out);
    pad_kernel<<<dim3(29, 8, NBATCH), 256, 0, stream>>>(feats, fpad);
    conv3x3_mfma<<<464, 512, 0, stream>>>(fpad, wbt, b3, conv1);
    head_mfma<<<463, 256, 0, stream>>>(conv1, wcb, bcls, bloc, out);
    iouloss_kernel<<<dim3(1, NBATCH), 256, 0, stream>>>(anchors, gtb, idxs, A, out, out);
}